// Round 5
// baseline (188.967 us; speedup 1.0000x reference)
//
#include <hip/hip_runtime.h>
#include <hip/hip_bf16.h>
#include <hip/hip_cooperative_groups.h>
#include <math.h>

namespace cg = cooperative_groups;

#define BATCH 32
#define WLEN  2048

typedef __attribute__((ext_vector_type(8))) short short8;
typedef __attribute__((ext_vector_type(4))) short short4v;
typedef __attribute__((ext_vector_type(4))) float floatx4;

__device__ inline short f2bf(float f) {
  unsigned u = __float_as_uint(f);
  unsigned r = (u + 0x7fffu + ((u >> 16) & 1u)) >> 16;
  return (short)r;
}

// ===========================================================================
// Cooperative single-kernel path.
// Grid (8, 32) x 512 threads; each block owns two adjacent 128-wide tiles.
// LDS: buf[2][16640] shorts — per tile, xs occupies [0, 8*130*8), y1 (written
// after MFMA reads complete) occupies the full [16][130][8].
// ===========================================================================
__global__ __launch_bounds__(512) void fused_all(
    const float* __restrict__ x,
    const float* __restrict__ w1, const float* __restrict__ b1,
    const float* __restrict__ fcw1, const float* __restrict__ fcb1,
    const float* __restrict__ g1, const float* __restrict__ be1,
    const float* __restrict__ rm1, const float* __restrict__ rv1,
    const float* __restrict__ w2, const float* __restrict__ b2,
    const float* __restrict__ fcw2, const float* __restrict__ fcb2,
    const float* __restrict__ g2, const float* __restrict__ be2,
    const float* __restrict__ rm2, const float* __restrict__ rv2,
    short* __restrict__ wp1, short* __restrict__ wp2,
    float* __restrict__ racc1, float* __restrict__ racc2,
    short* __restrict__ edges, float* __restrict__ out) {
  const int j = blockIdx.x;   // 0..7, super-tile of 256 w
  const int b = blockIdx.y;   // 0..31
  const int bid = b * 8 + j;
  const int tid = threadIdx.x;
  const int wave = tid >> 6, lane = tid & 63;
  const int ln = lane & 15, kg = lane >> 4;

  __shared__ short buf[2][16640];   // 66560 B
  __shared__ float red[512];        // 2048 B

  cg::grid_group grid = cg::this_grid();

  // ---------------- phase A: pack weights + stage x + routing1 ----------
  if (bid < 6) {         // wp1[k][ig8][o128][8], 3072 short8 items
    int iw = bid * 512 + tid;
    int o = iw & 127;
    int tt = iw >> 7;
    int ig = tt & 7;
    int k = tt >> 3;
    short8 v;
#pragma unroll
    for (int e = 0; e < 8; ++e) v[e] = f2bf(w1[(o * 64 + ig * 8 + e) * 3 + k]);
    *(short8*)(wp1 + (size_t)iw * 8) = v;
  } else if (bid < 30) { // wp2[k][ig16][o256][8], 12288 items
    int iw = (bid - 6) * 512 + tid;
    int o = iw & 255;
    int tt = iw >> 8;
    int ig = tt & 15;
    int k = tt >> 4;
    short8 v;
#pragma unroll
    for (int e = 0; e < 8; ++e) v[e] = f2bf(w2[(o * 128 + ig * 8 + e) * 3 + k]);
    *(short8*)(wp2 + (size_t)iw * 8) = v;
  }

  {
    const float* xb = x + (size_t)b * 64 * WLEN;
    float rsum = 0.f;
#pragma unroll
    for (int u = 0; u < 2; ++u) {
      const int w0 = j * 256 + u * 128;
      for (int idx = tid; idx < 8 * 130; idx += 512) {
        int ig = idx / 130;
        int p = idx - ig * 130;
        int w = w0 - 1 + p;
        short8 v = {0, 0, 0, 0, 0, 0, 0, 0};
        if ((unsigned)w < (unsigned)WLEN) {
          const float* src = xb + (size_t)(ig * 8) * WLEN + w;
          float fv[8];
#pragma unroll
          for (int e = 0; e < 8; ++e) fv[e] = src[(size_t)e * WLEN];
#pragma unroll
          for (int e = 0; e < 8; ++e) v[e] = f2bf(fv[e]);
          if (p >= 1 && p <= 128) {
#pragma unroll
            for (int e = 0; e < 8; ++e) rsum += fv[e] * fcw1[ig * 8 + e];
          }
        }
        *(short8*)(buf[u] + (size_t)idx * 8) = v;
      }
    }
    red[tid] = rsum;
    __syncthreads();
    for (int s = 256; s > 0; s >>= 1) {
      if (tid < s) red[tid] += red[tid + s];
      __syncthreads();
    }
    if (tid == 0) racc1[bid] = red[0];
  }
  __threadfence();
  grid.sync();

  // ---------------- phase B: conv1 on both tiles ----------
  {
    float zs = 0.f;
#pragma unroll
    for (int tt = 0; tt < 8; ++tt) zs += racc1[b * 8 + tt];
    float z = zs * (1.f / (float)WLEN) + fcb1[0];
    float r1v = 1.f / (1.f + expf(-z));

    const int oh = wave & 1, wq = wave >> 1;
    float rsum2 = 0.f;
#pragma unroll
    for (int u = 0; u < 2; ++u) {
      floatx4 acc[4][2];
#pragma unroll
      for (int ms = 0; ms < 4; ++ms)
#pragma unroll
        for (int ns = 0; ns < 2; ++ns) acc[ms][ns] = (floatx4){0.f, 0.f, 0.f, 0.f};

#pragma unroll
      for (int q = 0; q < 2; ++q) {
#pragma unroll
        for (int k = 0; k < 3; ++k) {
          short8 af[4];
          const short* wk =
              wp1 + ((size_t)(k * 8 + q * 4 + kg) * 128 + oh * 64 + ln) * 8;
#pragma unroll
          for (int ms = 0; ms < 4; ++ms)
            af[ms] = *(const short8*)(wk + (size_t)ms * 16 * 8);
#pragma unroll
          for (int ns = 0; ns < 2; ++ns) {
            short8 bf = *(const short8*)(
                buf[u] + ((q * 4 + kg) * 130 + wq * 32 + ns * 16 + ln + k) * 8);
#pragma unroll
            for (int ms = 0; ms < 4; ++ms)
              acc[ms][ns] = __builtin_amdgcn_mfma_f32_16x16x32_bf16(
                  af[ms], bf, acc[ms][ns], 0, 0, 0);
          }
        }
      }
      __syncthreads();  // all waves done reading xs[u] before y1 overwrite

#pragma unroll
      for (int ms = 0; ms < 4; ++ms) {
        const int o0 = oh * 64 + ms * 16 + kg * 4;
        float a_[4], c_[4], fw[4];
#pragma unroll
        for (int rr = 0; rr < 4; ++rr) {
          int o = o0 + rr;
          float s = g1[o] * rsqrtf(rv1[o] + 1e-5f);
          a_[rr] = r1v * s;
          c_[rr] = (r1v * b1[o] - rm1[o]) * s + be1[o];
          fw[rr] = fcw2[o];
        }
#pragma unroll
        for (int ns = 0; ns < 2; ++ns) {
          int lw = wq * 32 + ns * 16 + ln;  // 0..127
          short4v pk;
#pragma unroll
          for (int rr = 0; rr < 4; ++rr) {
            float v = acc[ms][ns][rr] * a_[rr] + c_[rr];
            v = v >= 0.f ? v : 0.1f * v;
            rsum2 += v * fw[rr];
            pk[rr] = f2bf(v);
          }
          *(short4v*)(buf[u] + ((o0 >> 3) * 130 + 1 + lw) * 8 + (o0 & 7)) = pk;
          if (u == 0 && lw == 0)
            *(short4v*)(edges + ((size_t)bid * 2 + 0) * 128 + o0) = pk;
          if (u == 1 && lw == 127)
            *(short4v*)(edges + ((size_t)bid * 2 + 1) * 128 + o0) = pk;
        }
      }
      __syncthreads();
    }
    red[tid] = rsum2;
    __syncthreads();
    for (int s = 256; s > 0; s >>= 1) {
      if (tid < s) red[tid] += red[tid + s];
      __syncthreads();
    }
    if (tid == 0) racc2[bid] = red[0];
  }
  __threadfence();
  grid.sync();

  // ---------------- phase C: conv2 on both tiles ----------
  {
    // halo columns
    if (tid < 128) {
      int c = tid;
      short v = 0;
      if (j > 0) v = edges[((size_t)(bid - 1) * 2 + 1) * 128 + c];
      buf[0][((c >> 3) * 130 + 0) * 8 + (c & 7)] = v;
    } else if (tid < 256) {
      int c = tid - 128;
      buf[0][((c >> 3) * 130 + 129) * 8 + (c & 7)] =
          buf[1][((c >> 3) * 130 + 1) * 8 + (c & 7)];
    } else if (tid < 384) {
      int c = tid - 256;
      buf[1][((c >> 3) * 130 + 0) * 8 + (c & 7)] =
          buf[0][((c >> 3) * 130 + 128) * 8 + (c & 7)];
    } else {
      int c = tid - 384;
      short v = 0;
      if (j < 7) v = edges[((size_t)(bid + 1) * 2 + 0) * 128 + c];
      buf[1][((c >> 3) * 130 + 129) * 8 + (c & 7)] = v;
    }
    __syncthreads();

    float zs = 0.f;
#pragma unroll
    for (int tt = 0; tt < 8; ++tt) zs += racc2[b * 8 + tt];
    float z = zs * (1.f / (float)WLEN) + fcb2[0];
    float r2v = 1.f / (1.f + expf(-z));

    const int oq = wave & 3, wh = wave >> 2;
#pragma unroll
    for (int u = 0; u < 2; ++u) {
      floatx4 acc[4][4];
#pragma unroll
      for (int ms = 0; ms < 4; ++ms)
#pragma unroll
        for (int ns = 0; ns < 4; ++ns) acc[ms][ns] = (floatx4){0.f, 0.f, 0.f, 0.f};

#pragma unroll
      for (int q = 0; q < 4; ++q) {
#pragma unroll
        for (int k = 0; k < 3; ++k) {
          short8 af[4];
          const short* wk =
              wp2 + ((size_t)(k * 16 + q * 4 + kg) * 256 + oq * 64 + ln) * 8;
#pragma unroll
          for (int ms = 0; ms < 4; ++ms)
            af[ms] = *(const short8*)(wk + (size_t)ms * 16 * 8);
#pragma unroll
          for (int ns = 0; ns < 4; ++ns) {
            short8 bf = *(const short8*)(
                buf[u] + ((q * 4 + kg) * 130 + wh * 64 + ns * 16 + ln + k) * 8);
#pragma unroll
            for (int ms = 0; ms < 4; ++ms)
              acc[ms][ns] = __builtin_amdgcn_mfma_f32_16x16x32_bf16(
                  af[ms], bf, acc[ms][ns], 0, 0, 0);
          }
        }
      }

      const int w0 = j * 256 + u * 128;
#pragma unroll
      for (int ms = 0; ms < 4; ++ms) {
        const int o0 = oq * 64 + ms * 16 + kg * 4;
        float a_[4], c_[4];
#pragma unroll
        for (int rr = 0; rr < 4; ++rr) {
          int o = o0 + rr;
          float s = g2[o] * rsqrtf(rv2[o] + 1e-5f);
          a_[rr] = r2v * s;
          c_[rr] = (r2v * b2[o] - rm2[o]) * s + be2[o];
        }
#pragma unroll
        for (int np = 0; np < 2; ++np) {
          float m0[4], m1[4];
#pragma unroll
          for (int half = 0; half < 2; ++half) {
            int ns = np * 2 + half;
#pragma unroll
            for (int rr = 0; rr < 4; ++rr) {
              float v = acc[ms][ns][rr] * a_[rr] + c_[rr];
              v = v >= 0.f ? v : 0.1f * v;
              float m = fmaxf(v, __shfl_xor(v, 1));
              if (half == 0) m0[rr] = m; else m1[rr] = m;
            }
          }
          const int pc = (w0 >> 1) + wh * 32 + np * 16 + ln;
#pragma unroll
          for (int rr = 0; rr < 4; ++rr) {
            int src = kg * 16 + ((ln & 7) << 1);
            float aa = __shfl(m0[rr], src);
            float bb = __shfl(m1[rr], src);
            float val = (ln < 8) ? aa : bb;
            out[((size_t)(b * 256 + o0 + rr)) * (WLEN / 2) + pc] = val;
          }
        }
      }
    }
  }
}

// ===========================================================================
// Fallback path (round-3 kernels, known good) — used only if the cooperative
// launch is rejected by the runtime.
// ===========================================================================
__global__ __launch_bounds__(256) void fused_prep(
    const float* __restrict__ w1, const float* __restrict__ w2,
    const float* __restrict__ x, const float* __restrict__ fcw1,
    short* __restrict__ wp1, short* __restrict__ wp2,
    float* __restrict__ racc1) {
  const int blk = blockIdx.x;
  const int tid = threadIdx.x;
  if (blk < 12) {
    int iw = blk * 256 + tid;
    int o = iw & 127;
    int t = iw >> 7;
    int ig = t & 7;
    int k = t >> 3;
    short8 v;
#pragma unroll
    for (int e = 0; e < 8; ++e) v[e] = f2bf(w1[(o * 64 + ig * 8 + e) * 3 + k]);
    *(short8*)(wp1 + (size_t)iw * 8) = v;
  } else if (blk < 60) {
    int iw = (blk - 12) * 256 + tid;
    int o = iw & 255;
    int t = iw >> 8;
    int ig = t & 15;
    int k = t >> 4;
    short8 v;
#pragma unroll
    for (int e = 0; e < 8; ++e) v[e] = f2bf(w2[(o * 128 + ig * 8 + e) * 3 + k]);
    *(short8*)(wp2 + (size_t)iw * 8) = v;
  } else {
    int t = blk - 60;
    int jj = t & 7, b = t >> 3;
    const float4* xb = (const float4*)(x + ((size_t)b * 64 + jj * 8) * WLEN);
    float sum = 0.f;
    for (int idx = tid; idx < 8 * 512; idx += 256) {
      int c = idx >> 9;
      float4 v = xb[idx];
      sum += (v.x + v.y + v.z + v.w) * fcw1[jj * 8 + c];
    }
    __shared__ float red[256];
    red[tid] = sum;
    __syncthreads();
    for (int s = 128; s > 0; s >>= 1) {
      if (tid < s) red[tid] += red[tid + s];
      __syncthreads();
    }
    if (tid == 0) racc1[b * 8 + jj] = red[0];
  }
}

__global__ __launch_bounds__(512) void fb_conv1(
    const float* __restrict__ x, const short* __restrict__ wp1,
    const float* __restrict__ bias, const float* __restrict__ g,
    const float* __restrict__ be, const float* __restrict__ rm,
    const float* __restrict__ rv, const float* __restrict__ racc1,
    const float* __restrict__ fcb, const float* __restrict__ fcw2,
    short* __restrict__ y1p, float* __restrict__ racc2) {
  const int b = blockIdx.y;
  const int w_base = blockIdx.x * 128;
  const int tid = threadIdx.x;
  const int wave = tid >> 6, lane = tid & 63;
  const int ln = lane & 15, kg = lane >> 4;
  const int oh = wave & 1, wq = wave >> 1;

  __shared__ short xs[8 * 130 * 8];
  __shared__ float red[512];

  const float* xb = x + (size_t)b * 64 * WLEN;
  for (int idx = tid; idx < 8 * 130; idx += 512) {
    int ig = idx / 130;
    int p = idx - ig * 130;
    int w = w_base - 1 + p;
    short8 v = {0, 0, 0, 0, 0, 0, 0, 0};
    if ((unsigned)w < (unsigned)WLEN) {
      const float* src = xb + (size_t)(ig * 8) * WLEN + w;
#pragma unroll
      for (int e = 0; e < 8; ++e) v[e] = f2bf(src[(size_t)e * WLEN]);
    }
    *(short8*)(xs + idx * 8) = v;
  }
  __syncthreads();

  floatx4 acc[4][2];
#pragma unroll
  for (int ms = 0; ms < 4; ++ms)
#pragma unroll
    for (int ns = 0; ns < 2; ++ns) acc[ms][ns] = (floatx4){0.f, 0.f, 0.f, 0.f};

#pragma unroll
  for (int q = 0; q < 2; ++q) {
#pragma unroll
    for (int k = 0; k < 3; ++k) {
      short8 af[4];
      const short* wk =
          wp1 + ((size_t)(k * 8 + q * 4 + kg) * 128 + oh * 64 + ln) * 8;
#pragma unroll
      for (int ms = 0; ms < 4; ++ms)
        af[ms] = *(const short8*)(wk + (size_t)ms * 16 * 8);
#pragma unroll
      for (int ns = 0; ns < 2; ++ns) {
        short8 bf = *(const short8*)(
            xs + ((q * 4 + kg) * 130 + wq * 32 + ns * 16 + ln + k) * 8);
#pragma unroll
        for (int ms = 0; ms < 4; ++ms)
          acc[ms][ns] = __builtin_amdgcn_mfma_f32_16x16x32_bf16(
              af[ms], bf, acc[ms][ns], 0, 0, 0);
      }
    }
  }

  float zs = 0.f;
#pragma unroll
  for (int qq = 0; qq < 8; ++qq) zs += racc1[b * 8 + qq];
  float z = zs * (1.f / (float)WLEN) + fcb[0];
  float r1v = 1.f / (1.f + expf(-z));

  float rsum2 = 0.f;
#pragma unroll
  for (int ms = 0; ms < 4; ++ms) {
    const int o0 = oh * 64 + ms * 16 + kg * 4;
    float a_[4], c_[4], fw[4];
#pragma unroll
    for (int rr = 0; rr < 4; ++rr) {
      int o = o0 + rr;
      float s = g[o] * rsqrtf(rv[o] + 1e-5f);
      a_[rr] = r1v * s;
      c_[rr] = (r1v * bias[o] - rm[o]) * s + be[o];
      fw[rr] = fcw2[o];
    }
#pragma unroll
    for (int ns = 0; ns < 2; ++ns) {
      int lw = wq * 32 + ns * 16 + ln;
      short4v pk;
#pragma unroll
      for (int rr = 0; rr < 4; ++rr) {
        float v = acc[ms][ns][rr] * a_[rr] + c_[rr];
        v = v >= 0.f ? v : 0.1f * v;
        rsum2 += v * fw[rr];
        pk[rr] = f2bf(v);
      }
      *(short4v*)(y1p + ((size_t)(b * 32 + (o0 >> 2)) * WLEN + w_base + lw) * 4) = pk;
    }
  }
  red[tid] = rsum2;
  __syncthreads();
  for (int s = 256; s > 0; s >>= 1) {
    if (tid < s) red[tid] += red[tid + s];
    __syncthreads();
  }
  if (tid == 0) racc2[b * 16 + blockIdx.x] = red[0];
}

__global__ __launch_bounds__(512) void fb_conv2(
    const short* __restrict__ y1p, const short* __restrict__ wp2,
    const float* __restrict__ bias, const float* __restrict__ g,
    const float* __restrict__ be, const float* __restrict__ rm,
    const float* __restrict__ rv, const float* __restrict__ racc2,
    const float* __restrict__ fcb, float* __restrict__ out) {
  const int b = blockIdx.y;
  const int w_base = blockIdx.x * 128;
  const int tid = threadIdx.x;
  const int wave = tid >> 6, lane = tid & 63;
  const int ln = lane & 15, kg = lane >> 4;
  const int oq = wave & 3, wh = wave >> 2;

  __shared__ short xs[16 * 130 * 8];

  const short* yb = y1p + (size_t)b * 32 * WLEN * 4;
  for (int idx = tid; idx < 16 * 130; idx += 512) {
    int ig = idx / 130;
    int p = idx - ig * 130;
    int w = w_base - 1 + p;
    short8 v = {0, 0, 0, 0, 0, 0, 0, 0};
    if ((unsigned)w < (unsigned)WLEN) {
      short4v a = *(const short4v*)(yb + ((size_t)(ig * 2) * WLEN + w) * 4);
      short4v c = *(const short4v*)(yb + ((size_t)(ig * 2 + 1) * WLEN + w) * 4);
      v[0] = a[0]; v[1] = a[1]; v[2] = a[2]; v[3] = a[3];
      v[4] = c[0]; v[5] = c[1]; v[6] = c[2]; v[7] = c[3];
    }
    *(short8*)(xs + idx * 8) = v;
  }
  __syncthreads();

  floatx4 acc[4][4];
#pragma unroll
  for (int ms = 0; ms < 4; ++ms)
#pragma unroll
    for (int ns = 0; ns < 4; ++ns) acc[ms][ns] = (floatx4){0.f, 0.f, 0.f, 0.f};

#pragma unroll
  for (int q = 0; q < 4; ++q) {
#pragma unroll
    for (int k = 0; k < 3; ++k) {
      short8 af[4];
      const short* wk =
          wp2 + ((size_t)(k * 16 + q * 4 + kg) * 256 + oq * 64 + ln) * 8;
#pragma unroll
      for (int ms = 0; ms < 4; ++ms)
        af[ms] = *(const short8*)(wk + (size_t)ms * 16 * 8);
#pragma unroll
      for (int ns = 0; ns < 4; ++ns) {
        short8 bf = *(const short8*)(
            xs + ((q * 4 + kg) * 130 + wh * 64 + ns * 16 + ln + k) * 8);
#pragma unroll
        for (int ms = 0; ms < 4; ++ms)
          acc[ms][ns] = __builtin_amdgcn_mfma_f32_16x16x32_bf16(
              af[ms], bf, acc[ms][ns], 0, 0, 0);
      }
    }
  }

  float zs = 0.f;
#pragma unroll
  for (int t = 0; t < 16; ++t) zs += racc2[b * 16 + t];
  float z = zs * (1.f / (float)WLEN) + fcb[0];
  float r2v = 1.f / (1.f + expf(-z));

#pragma unroll
  for (int ms = 0; ms < 4; ++ms) {
    const int o0 = oq * 64 + ms * 16 + kg * 4;
    float a_[4], c_[4];
#pragma unroll
    for (int rr = 0; rr < 4; ++rr) {
      int o = o0 + rr;
      float s = g[o] * rsqrtf(rv[o] + 1e-5f);
      a_[rr] = r2v * s;
      c_[rr] = (r2v * bias[o] - rm[o]) * s + be[o];
    }
#pragma unroll
    for (int np = 0; np < 2; ++np) {
      float m0[4], m1[4];
#pragma unroll
      for (int half = 0; half < 2; ++half) {
        int ns = np * 2 + half;
#pragma unroll
        for (int rr = 0; rr < 4; ++rr) {
          float v = acc[ms][ns][rr] * a_[rr] + c_[rr];
          v = v >= 0.f ? v : 0.1f * v;
          float m = fmaxf(v, __shfl_xor(v, 1));
          if (half == 0) m0[rr] = m; else m1[rr] = m;
        }
      }
      const int pc = (w_base >> 1) + wh * 32 + np * 16 + ln;
#pragma unroll
      for (int rr = 0; rr < 4; ++rr) {
        int src = kg * 16 + ((ln & 7) << 1);
        float aa = __shfl(m0[rr], src);
        float bb = __shfl(m1[rr], src);
        float val = (ln < 8) ? aa : bb;
        out[((size_t)(b * 256 + o0 + rr)) * (WLEN / 2) + pc] = val;
      }
    }
  }
}

// ---------------------------------------------------------------------------
extern "C" void kernel_launch(void* const* d_in, const int* in_sizes, int n_in,
                              void* d_out, int out_size, void* d_ws, size_t ws_size,
                              hipStream_t stream) {
  const float* x    = (const float*)d_in[0];
  const float* w1   = (const float*)d_in[1];
  const float* b1   = (const float*)d_in[2];
  const float* fcw1 = (const float*)d_in[3];
  const float* fcb1 = (const float*)d_in[4];
  const float* g1   = (const float*)d_in[5];
  const float* be1  = (const float*)d_in[6];
  const float* rm1  = (const float*)d_in[7];
  const float* rv1  = (const float*)d_in[8];
  const float* w2   = (const float*)d_in[9];
  const float* b2   = (const float*)d_in[10];
  const float* fcw2 = (const float*)d_in[11];
  const float* fcb2 = (const float*)d_in[12];
  const float* g2   = (const float*)d_in[13];
  const float* be2  = (const float*)d_in[14];
  const float* rm2  = (const float*)d_in[15];
  const float* rv2  = (const float*)d_in[16];
  float* out = (float*)d_out;

  char* ws = (char*)d_ws;
  short* wp1   = (short*)(ws);                        // 49152 B
  short* wp2   = (short*)(ws + 65536);                // 196608 B
  float* racc1 = (float*)(ws + 262144);               // 2048 B
  float* racc2 = (float*)(ws + 264192);               // 2048 B
  short* edges = (short*)(ws + 266240);               // 131072 B
  short* y1p   = (short*)(ws + (size_t)1024 * 1024);  // 16 MiB (fallback only)

  void* args[] = {
      (void*)&x,
      (void*)&w1, (void*)&b1, (void*)&fcw1, (void*)&fcb1,
      (void*)&g1, (void*)&be1, (void*)&rm1, (void*)&rv1,
      (void*)&w2, (void*)&b2, (void*)&fcw2, (void*)&fcb2,
      (void*)&g2, (void*)&be2, (void*)&rm2, (void*)&rv2,
      (void*)&wp1, (void*)&wp2, (void*)&racc1, (void*)&racc2,
      (void*)&edges, (void*)&out};

  hipError_t err = hipLaunchCooperativeKernel(
      (const void*)fused_all, dim3(8, 32), dim3(512), args, 0, stream);
  if (err != hipSuccess) {
    (void)hipGetLastError();  // clear error state
    fused_prep<<<316, 256, 0, stream>>>(w1, w2, x, fcw1, wp1, wp2, racc1);
    fb_conv1<<<dim3(16, 32), 512, 0, stream>>>(
        x, wp1, b1, g1, be1, rm1, rv1, racc1, fcb1, fcw2, y1p, racc2);
    fb_conv2<<<dim3(16, 32), 512, 0, stream>>>(
        y1p, wp2, b2, g2, be2, rm2, rv2, racc2, fcb2, out);
  }
}

// Round 6
// 55.935 us; speedup vs baseline: 3.3783x; 3.3783x over previous
//
#include <hip/hip_runtime.h>
#include <hip/hip_bf16.h>
#include <math.h>

#define BATCH 32
#define WLEN  2048

typedef __attribute__((ext_vector_type(8))) short short8;
typedef __attribute__((ext_vector_type(4))) short short4v;
typedef __attribute__((ext_vector_type(4))) float floatx4;

__device__ inline short f2bf(float f) {
  unsigned u = __float_as_uint(f);
  unsigned r = (u + 0x7fffu + ((u >> 16) & 1u)) >> 16;
  return (short)r;
}

// ---------------------------------------------------------------------------
// fused prep: blocks 0..11 pack w1 -> wp1[k][ig8][o128][8]
//             blocks 12..59 pack w2 -> wp2[k][ig16][o256][8]
//             blocks 60..315 routing1 partials racc1[b*8+j]
// ---------------------------------------------------------------------------
__global__ __launch_bounds__(256) void fused_prep(
    const float* __restrict__ w1, const float* __restrict__ w2,
    const float* __restrict__ x, const float* __restrict__ fcw1,
    short* __restrict__ wp1, short* __restrict__ wp2,
    float* __restrict__ racc1) {
  const int blk = blockIdx.x;
  const int tid = threadIdx.x;
  if (blk < 12) {
    int iw = blk * 256 + tid;          // (k, ig, o) over 3*8*128
    int o = iw & 127;
    int t = iw >> 7;
    int ig = t & 7;
    int k = t >> 3;
    short8 v;
#pragma unroll
    for (int e = 0; e < 8; ++e) v[e] = f2bf(w1[(o * 64 + ig * 8 + e) * 3 + k]);
    *(short8*)(wp1 + (size_t)iw * 8) = v;
  } else if (blk < 60) {
    int iw = (blk - 12) * 256 + tid;   // (k, ig, o) over 3*16*256
    int o = iw & 255;
    int t = iw >> 8;
    int ig = t & 15;
    int k = t >> 4;
    short8 v;
#pragma unroll
    for (int e = 0; e < 8; ++e) v[e] = f2bf(w2[(o * 128 + ig * 8 + e) * 3 + k]);
    *(short8*)(wp2 + (size_t)iw * 8) = v;
  } else {
    int t = blk - 60;
    int j = t & 7, b = t >> 3;
    const float4* xb = (const float4*)(x + ((size_t)b * 64 + j * 8) * WLEN);
    float sum = 0.f;
    for (int idx = tid; idx < 8 * 512; idx += 256) {
      int c = idx >> 9;
      float4 v = xb[idx];
      sum += (v.x + v.y + v.z + v.w) * fcw1[j * 8 + c];
    }
    __shared__ float red[256];
    red[tid] = sum;
    __syncthreads();
    for (int s = 128; s > 0; s >>= 1) {
      if (tid < s) red[tid] += red[tid + s];
      __syncthreads();
    }
    if (tid == 0) racc1[b * 8 + j] = red[0];
  }
}

// ---------------------------------------------------------------------------
// conv1: x fp32 (B,64,W) -> y1p bf16 [b][o/8][w][8], + routing2 partials.
// 256 threads (4 waves), tile 128o x 64w; wave = 64o x 32w (4ms x 2ns).
// grid (32, 32) = 1024 blocks -> 4 blocks/CU, 16 waves/CU.
// ---------------------------------------------------------------------------
__global__ __launch_bounds__(256) void conv1_mfma(
    const float* __restrict__ x, const short* __restrict__ wp1,
    const float* __restrict__ bias, const float* __restrict__ g,
    const float* __restrict__ be, const float* __restrict__ rm,
    const float* __restrict__ rv, const float* __restrict__ racc1,
    const float* __restrict__ fcb, const float* __restrict__ fcw2,
    short* __restrict__ y1p, float* __restrict__ racc2) {
  const int b = blockIdx.y;
  const int wt = blockIdx.x;
  const int w0 = wt * 64;
  const int tid = threadIdx.x;
  const int wave = tid >> 6, lane = tid & 63;
  const int ln = lane & 15, kg = lane >> 4;
  const int oh = wave & 1, wq = wave >> 1;

  __shared__ short xs[8 * 66 * 8];   // 8.4 KB, [ig][p][e], p = w0-1 .. w0+64
  __shared__ float red[256];

  const float* xb = x + (size_t)b * 64 * WLEN;
  for (int idx = tid; idx < 8 * 66; idx += 256) {
    int ig = idx / 66;
    int p = idx - ig * 66;
    int w = w0 - 1 + p;
    short8 v = {0, 0, 0, 0, 0, 0, 0, 0};
    if ((unsigned)w < (unsigned)WLEN) {
      const float* src = xb + (size_t)(ig * 8) * WLEN + w;
#pragma unroll
      for (int e = 0; e < 8; ++e) v[e] = f2bf(src[(size_t)e * WLEN]);
    }
    *(short8*)(xs + idx * 8) = v;
  }
  __syncthreads();

  floatx4 acc[4][2];
#pragma unroll
  for (int ms = 0; ms < 4; ++ms)
#pragma unroll
    for (int ns = 0; ns < 2; ++ns) acc[ms][ns] = (floatx4){0.f, 0.f, 0.f, 0.f};

#pragma unroll
  for (int q = 0; q < 2; ++q) {
#pragma unroll
    for (int k = 0; k < 3; ++k) {
      short8 af[4];
      const short* wk =
          wp1 + ((size_t)(k * 8 + q * 4 + kg) * 128 + oh * 64 + ln) * 8;
#pragma unroll
      for (int ms = 0; ms < 4; ++ms)
        af[ms] = *(const short8*)(wk + (size_t)ms * 16 * 8);
#pragma unroll
      for (int ns = 0; ns < 2; ++ns) {
        short8 bf = *(const short8*)(
            xs + ((q * 4 + kg) * 66 + wq * 32 + ns * 16 + ln + k) * 8);
#pragma unroll
        for (int ms = 0; ms < 4; ++ms)
          acc[ms][ns] = __builtin_amdgcn_mfma_f32_16x16x32_bf16(
              af[ms], bf, acc[ms][ns], 0, 0, 0);
      }
    }
  }

  // r1
  float zs = 0.f;
#pragma unroll
  for (int qq = 0; qq < 8; ++qq) zs += racc1[b * 8 + qq];
  float z = zs * (1.f / (float)WLEN) + fcb[0];
  float r1v = 1.f / (1.f + expf(-z));

  float rsum2 = 0.f;
#pragma unroll
  for (int ms = 0; ms < 4; ++ms) {
    const int o0 = oh * 64 + ms * 16 + kg * 4;
    float a_[4], c_[4], fw[4];
#pragma unroll
    for (int rr = 0; rr < 4; ++rr) {
      int o = o0 + rr;
      float s = g[o] * rsqrtf(rv[o] + 1e-5f);
      a_[rr] = r1v * s;
      c_[rr] = (r1v * bias[o] - rm[o]) * s + be[o];
      fw[rr] = fcw2[o];
    }
#pragma unroll
    for (int ns = 0; ns < 2; ++ns) {
      int w = w0 + wq * 32 + ns * 16 + ln;
      short4v pk;
#pragma unroll
      for (int rr = 0; rr < 4; ++rr) {
        float v = acc[ms][ns][rr] * a_[rr] + c_[rr];
        v = v >= 0.f ? v : 0.1f * v;
        rsum2 += v * fw[rr];
        pk[rr] = f2bf(v);
      }
      // y1p layout [b][o/8][w][8]
      *(short4v*)(y1p + ((size_t)(b * 16 + (o0 >> 3)) * WLEN + w) * 8 + (o0 & 7)) = pk;
    }
  }
  red[tid] = rsum2;
  __syncthreads();
  for (int s = 128; s > 0; s >>= 1) {
    if (tid < s) red[tid] += red[tid + s];
    __syncthreads();
  }
  if (tid == 0) racc2[b * 32 + wt] = red[0];
}

// ---------------------------------------------------------------------------
// conv2: y1p bf16 [b][ig16][w][8] -> out fp32 pooled (B,256,1024).
// 512 threads (8 waves), tile 256o x 64w; wave = 64o x 32w (4ms x 2ns).
// grid (32, 32) = 1024 blocks -> 4 blocks/CU, 32 waves/CU.
// ---------------------------------------------------------------------------
__global__ __launch_bounds__(512) void conv2_mfma(
    const short* __restrict__ y1p, const short* __restrict__ wp2,
    const float* __restrict__ bias, const float* __restrict__ g,
    const float* __restrict__ be, const float* __restrict__ rm,
    const float* __restrict__ rv, const float* __restrict__ racc2,
    const float* __restrict__ fcb, float* __restrict__ out) {
  const int b = blockIdx.y;
  const int w0 = blockIdx.x * 64;
  const int tid = threadIdx.x;
  const int wave = tid >> 6, lane = tid & 63;
  const int ln = lane & 15, kg = lane >> 4;
  const int oq = wave & 3, wh = wave >> 2;

  __shared__ short xs[16 * 66 * 8];  // 16.9 KB

  const short* yb = y1p + (size_t)b * 16 * WLEN * 8;
  for (int idx = tid; idx < 16 * 66; idx += 512) {
    int ig = idx / 66;
    int p = idx - ig * 66;
    int w = w0 - 1 + p;
    short8 v = {0, 0, 0, 0, 0, 0, 0, 0};
    if ((unsigned)w < (unsigned)WLEN)
      v = *(const short8*)(yb + ((size_t)ig * WLEN + w) * 8);
    *(short8*)(xs + idx * 8) = v;
  }
  __syncthreads();

  floatx4 acc[4][2];
#pragma unroll
  for (int ms = 0; ms < 4; ++ms)
#pragma unroll
    for (int ns = 0; ns < 2; ++ns) acc[ms][ns] = (floatx4){0.f, 0.f, 0.f, 0.f};

#pragma unroll
  for (int q = 0; q < 4; ++q) {
#pragma unroll
    for (int k = 0; k < 3; ++k) {
      short8 af[4];
      const short* wk =
          wp2 + ((size_t)(k * 16 + q * 4 + kg) * 256 + oq * 64 + ln) * 8;
#pragma unroll
      for (int ms = 0; ms < 4; ++ms)
        af[ms] = *(const short8*)(wk + (size_t)ms * 16 * 8);
#pragma unroll
      for (int ns = 0; ns < 2; ++ns) {
        short8 bf = *(const short8*)(
            xs + ((q * 4 + kg) * 66 + wh * 32 + ns * 16 + ln + k) * 8);
#pragma unroll
        for (int ms = 0; ms < 4; ++ms)
          acc[ms][ns] = __builtin_amdgcn_mfma_f32_16x16x32_bf16(
              af[ms], bf, acc[ms][ns], 0, 0, 0);
      }
    }
  }

  // r2
  float zs = 0.f;
#pragma unroll
  for (int t = 0; t < 32; ++t) zs += racc2[b * 32 + t];
  float z = zs * (1.f / (float)WLEN) + fcb[0];
  float r2v = 1.f / (1.f + expf(-z));

#pragma unroll
  for (int ms = 0; ms < 4; ++ms) {
    const int o0 = oq * 64 + ms * 16 + kg * 4;
    float a_[4], c_[4];
#pragma unroll
    for (int rr = 0; rr < 4; ++rr) {
      int o = o0 + rr;
      float s = g[o] * rsqrtf(rv[o] + 1e-5f);
      a_[rr] = r2v * s;
      c_[rr] = (r2v * bias[o] - rm[o]) * s + be[o];
    }
    float m0[4], m1[4];
#pragma unroll
    for (int half = 0; half < 2; ++half) {
#pragma unroll
      for (int rr = 0; rr < 4; ++rr) {
        float v = acc[ms][half][rr] * a_[rr] + c_[rr];
        v = v >= 0.f ? v : 0.1f * v;
        float m = fmaxf(v, __shfl_xor(v, 1));
        if (half == 0) m0[rr] = m; else m1[rr] = m;
      }
    }
    const int pc = (w0 >> 1) + wh * 16 + ln;
#pragma unroll
    for (int rr = 0; rr < 4; ++rr) {
      int src = kg * 16 + ((ln & 7) << 1);
      float aa = __shfl(m0[rr], src);
      float bb = __shfl(m1[rr], src);
      float val = (ln < 8) ? aa : bb;
      out[((size_t)(b * 256 + o0 + rr)) * (WLEN / 2) + pc] = val;
    }
  }
}

// ---------------------------------------------------------------------------
extern "C" void kernel_launch(void* const* d_in, const int* in_sizes, int n_in,
                              void* d_out, int out_size, void* d_ws, size_t ws_size,
                              hipStream_t stream) {
  const float* x    = (const float*)d_in[0];
  const float* w1   = (const float*)d_in[1];
  const float* b1   = (const float*)d_in[2];
  const float* fcw1 = (const float*)d_in[3];
  const float* fcb1 = (const float*)d_in[4];
  const float* g1   = (const float*)d_in[5];
  const float* be1  = (const float*)d_in[6];
  const float* rm1  = (const float*)d_in[7];
  const float* rv1  = (const float*)d_in[8];
  const float* w2   = (const float*)d_in[9];
  const float* b2   = (const float*)d_in[10];
  const float* fcw2 = (const float*)d_in[11];
  const float* fcb2 = (const float*)d_in[12];
  const float* g2   = (const float*)d_in[13];
  const float* be2  = (const float*)d_in[14];
  const float* rm2  = (const float*)d_in[15];
  const float* rv2  = (const float*)d_in[16];
  float* out = (float*)d_out;

  char* ws = (char*)d_ws;
  short* y1p   = (short*)ws;                          // 32*16*2048*8*2 = 16 MiB
  short* wp1   = (short*)(ws + (size_t)16 * 1024 * 1024);            // 48 KiB
  short* wp2   = (short*)(ws + (size_t)16 * 1024 * 1024 + 65536);    // 192 KiB
  float* racc1 = (float*)(ws + (size_t)16 * 1024 * 1024 + 327680);   // 256 f
  float* racc2 = racc1 + 256;                                        // 1024 f

  fused_prep<<<316, 256, 0, stream>>>(w1, w2, x, fcw1, wp1, wp2, racc1);
  conv1_mfma<<<dim3(32, 32), 256, 0, stream>>>(
      x, wp1, b1, g1, be1, rm1, rv1, racc1, fcb1, fcw2, y1p, racc2);
  conv2_mfma<<<dim3(32, 32), 512, 0, stream>>>(
      y1p, wp2, b2, g2, be2, rm2, rv2, racc2, fcb2, out);
}

// Round 7
// 54.505 us; speedup vs baseline: 3.4670x; 1.0262x over previous
//
#include <hip/hip_runtime.h>
#include <hip/hip_bf16.h>
#include <math.h>

#define BATCH 32
#define WLEN  2048

typedef __attribute__((ext_vector_type(8))) short short8;
typedef __attribute__((ext_vector_type(4))) short short4v;
typedef __attribute__((ext_vector_type(4))) float floatx4;

__device__ inline short f2bf(float f) {
  unsigned u = __float_as_uint(f);
  unsigned r = (u + 0x7fffu + ((u >> 16) & 1u)) >> 16;
  return (short)r;
}

// ---------------------------------------------------------------------------
// fused prep: blocks 0..11 pack w1 -> wp1[k][ig8][o128][8]
//             blocks 12..59 pack w2 -> wp2[k][ig16][o256][8]
//             blocks 60..315 routing1 partials racc1[b*8+j]
// ---------------------------------------------------------------------------
__global__ __launch_bounds__(256) void fused_prep(
    const float* __restrict__ w1, const float* __restrict__ w2,
    const float* __restrict__ x, const float* __restrict__ fcw1,
    short* __restrict__ wp1, short* __restrict__ wp2,
    float* __restrict__ racc1) {
  const int blk = blockIdx.x;
  const int tid = threadIdx.x;
  if (blk < 12) {
    int iw = blk * 256 + tid;          // (k, ig, o) over 3*8*128
    int o = iw & 127;
    int t = iw >> 7;
    int ig = t & 7;
    int k = t >> 3;
    short8 v;
#pragma unroll
    for (int e = 0; e < 8; ++e) v[e] = f2bf(w1[(o * 64 + ig * 8 + e) * 3 + k]);
    *(short8*)(wp1 + (size_t)iw * 8) = v;
  } else if (blk < 60) {
    int iw = (blk - 12) * 256 + tid;   // (k, ig, o) over 3*16*256
    int o = iw & 255;
    int t = iw >> 8;
    int ig = t & 15;
    int k = t >> 4;
    short8 v;
#pragma unroll
    for (int e = 0; e < 8; ++e) v[e] = f2bf(w2[(o * 128 + ig * 8 + e) * 3 + k]);
    *(short8*)(wp2 + (size_t)iw * 8) = v;
  } else {
    int t = blk - 60;
    int j = t & 7, b = t >> 3;
    const float4* xb = (const float4*)(x + ((size_t)b * 64 + j * 8) * WLEN);
    float sum = 0.f;
    for (int idx = tid; idx < 8 * 512; idx += 256) {
      int c = idx >> 9;
      float4 v = xb[idx];
      sum += (v.x + v.y + v.z + v.w) * fcw1[j * 8 + c];
    }
    __shared__ float red[256];
    red[tid] = sum;
    __syncthreads();
    for (int s = 128; s > 0; s >>= 1) {
      if (tid < s) red[tid] += red[tid + s];
      __syncthreads();
    }
    if (tid == 0) racc1[b * 8 + j] = red[0];
  }
}

// ---------------------------------------------------------------------------
// conv1: x fp32 (B,64,W) -> y1p bf16 [b][o/8][w][8], + routing2 partials.
// 512 threads (8 waves), tile 128o x 128w; wave = 64o x 32w (4ms x 2ns).
// Weights (48KB) fully LDS-resident. grid (16,32) -> 2 blocks/CU.
// ---------------------------------------------------------------------------
__global__ __launch_bounds__(512, 4) void conv1_mfma(
    const float* __restrict__ x, const short* __restrict__ wp1,
    const float* __restrict__ bias, const float* __restrict__ g,
    const float* __restrict__ be, const float* __restrict__ rm,
    const float* __restrict__ rv, const float* __restrict__ racc1,
    const float* __restrict__ fcb, const float* __restrict__ fcw2,
    short* __restrict__ y1p, float* __restrict__ racc2) {
  const int b = blockIdx.y;
  const int w0 = blockIdx.x * 128;
  const int tid = threadIdx.x;
  const int wave = tid >> 6, lane = tid & 63;
  const int ln = lane & 15, kg = lane >> 4;
  const int oh = wave & 1, wq = wave >> 1;

  __shared__ short wl[3 * 8 * 128 * 8];  // 48 KB, [k][ig][o][e]
  __shared__ short xs[8 * 130 * 8];      // 16.6 KB, [ig][p][e]
  __shared__ float red[512];             // 2 KB

  // stage weights (once) — 3072 short8 items, 6 per thread
  for (int i = tid; i < 3072; i += 512)
    *(short8*)(wl + (size_t)i * 8) = *(const short8*)(wp1 + (size_t)i * 8);

  // stage x tile (fp32 -> bf16), halo of 1
  const float* xb = x + (size_t)b * 64 * WLEN;
  for (int idx = tid; idx < 8 * 130; idx += 512) {
    int ig = idx / 130;
    int p = idx - ig * 130;
    int w = w0 - 1 + p;
    short8 v = {0, 0, 0, 0, 0, 0, 0, 0};
    if ((unsigned)w < (unsigned)WLEN) {
      const float* src = xb + (size_t)(ig * 8) * WLEN + w;
#pragma unroll
      for (int e = 0; e < 8; ++e) v[e] = f2bf(src[(size_t)e * WLEN]);
    }
    *(short8*)(xs + idx * 8) = v;
  }
  __syncthreads();

  floatx4 acc[4][2];
#pragma unroll
  for (int ms = 0; ms < 4; ++ms)
#pragma unroll
    for (int ns = 0; ns < 2; ++ns) acc[ms][ns] = (floatx4){0.f, 0.f, 0.f, 0.f};

#pragma unroll
  for (int q = 0; q < 2; ++q) {
#pragma unroll
    for (int k = 0; k < 3; ++k) {
      short8 af[4], bf[2];
      const short* wk = wl + ((size_t)(k * 8 + q * 4 + kg) * 128 + oh * 64 + ln) * 8;
#pragma unroll
      for (int ms = 0; ms < 4; ++ms)
        af[ms] = *(const short8*)(wk + (size_t)ms * 16 * 8);
#pragma unroll
      for (int ns = 0; ns < 2; ++ns)
        bf[ns] = *(const short8*)(
            xs + ((q * 4 + kg) * 130 + wq * 32 + ns * 16 + ln + k) * 8);
#pragma unroll
      for (int ms = 0; ms < 4; ++ms)
#pragma unroll
        for (int ns = 0; ns < 2; ++ns)
          acc[ms][ns] = __builtin_amdgcn_mfma_f32_16x16x32_bf16(
              af[ms], bf[ns], acc[ms][ns], 0, 0, 0);
    }
  }

  // r1
  float zs = 0.f;
#pragma unroll
  for (int qq = 0; qq < 8; ++qq) zs += racc1[b * 8 + qq];
  float z = zs * (1.f / (float)WLEN) + fcb[0];
  float r1v = 1.f / (1.f + expf(-z));

  float rsum2 = 0.f;
#pragma unroll
  for (int ms = 0; ms < 4; ++ms) {
    const int o0 = oh * 64 + ms * 16 + kg * 4;
    float a_[4], c_[4], fw[4];
#pragma unroll
    for (int rr = 0; rr < 4; ++rr) {
      int o = o0 + rr;
      float s = g[o] * rsqrtf(rv[o] + 1e-5f);
      a_[rr] = r1v * s;
      c_[rr] = (r1v * bias[o] - rm[o]) * s + be[o];
      fw[rr] = fcw2[o];
    }
#pragma unroll
    for (int ns = 0; ns < 2; ++ns) {
      int w = w0 + wq * 32 + ns * 16 + ln;
      short4v pk;
#pragma unroll
      for (int rr = 0; rr < 4; ++rr) {
        float v = acc[ms][ns][rr] * a_[rr] + c_[rr];
        v = v >= 0.f ? v : 0.1f * v;
        rsum2 += v * fw[rr];
        pk[rr] = f2bf(v);
      }
      // y1p layout [b][o/8][w][8]
      *(short4v*)(y1p + ((size_t)(b * 16 + (o0 >> 3)) * WLEN + w) * 8 + (o0 & 7)) = pk;
    }
  }
  red[tid] = rsum2;
  __syncthreads();
  for (int s = 256; s > 0; s >>= 1) {
    if (tid < s) red[tid] += red[tid + s];
    __syncthreads();
  }
  if (tid == 0) racc2[b * 16 + blockIdx.x] = red[0];
}

// ---------------------------------------------------------------------------
// conv2: y1p bf16 [b][ig16][w][8] -> out fp32 pooled (B,256,1024).
// 512 threads (8 waves), tile 256o x 128w; wave = 64o x 64w (4ms x 4ns).
// Weights LDS-staged per (q,k) chunk (16KB), double-buffered with prefetch.
// grid (16,32) -> 2 blocks/CU.
// ---------------------------------------------------------------------------
__global__ __launch_bounds__(512, 4) void conv2_mfma(
    const short* __restrict__ y1p, const short* __restrict__ wp2,
    const float* __restrict__ bias, const float* __restrict__ g,
    const float* __restrict__ be, const float* __restrict__ rm,
    const float* __restrict__ rv, const float* __restrict__ racc2,
    const float* __restrict__ fcb, float* __restrict__ out) {
  const int b = blockIdx.y;
  const int w0 = blockIdx.x * 128;
  const int tid = threadIdx.x;
  const int wave = tid >> 6, lane = tid & 63;
  const int ln = lane & 15, kg = lane >> 4;
  const int oq = wave & 3, wh = wave >> 2;

  __shared__ short xs[16 * 130 * 8];   // 33.3 KB
  __shared__ short wbuf[2][8192];      // 32 KB, chunk = [4ig][256o][8e]

  // stage x tile
  const short* yb = y1p + (size_t)b * 16 * WLEN * 8;
  for (int idx = tid; idx < 16 * 130; idx += 512) {
    int ig = idx / 130;
    int p = idx - ig * 130;
    int w = w0 - 1 + p;
    short8 v = {0, 0, 0, 0, 0, 0, 0, 0};
    if ((unsigned)w < (unsigned)WLEN)
      v = *(const short8*)(yb + ((size_t)ig * WLEN + w) * 8);
    *(short8*)(xs + idx * 8) = v;
  }

  // stage weight chunk 0 (q=0,k=0 -> rows 0..3): 1024 short8, 2 per thread
  {
    const short* src = wp2;  // row0 = 0
    *(short8*)(wbuf[0] + (size_t)(0 * 512 + tid) * 8) =
        *(const short8*)(src + (size_t)(0 * 512 + tid) * 8);
    *(short8*)(wbuf[0] + (size_t)(1 * 512 + tid) * 8) =
        *(const short8*)(src + (size_t)(1 * 512 + tid) * 8);
  }
  __syncthreads();

  floatx4 acc[4][4];
#pragma unroll
  for (int ms = 0; ms < 4; ++ms)
#pragma unroll
    for (int ns = 0; ns < 4; ++ns) acc[ms][ns] = (floatx4){0.f, 0.f, 0.f, 0.f};

#pragma unroll
  for (int c = 0; c < 12; ++c) {
    const int cur = c & 1;
    const int q = c / 3, k = c % 3;

    // prefetch next chunk into registers (issued before MFMA cluster)
    short8 nreg0, nreg1;
    if (c < 11) {
      const int nq = (c + 1) / 3, nk = (c + 1) % 3;
      const short* src = wp2 + (size_t)(nk * 16 + nq * 4) * 256 * 8;
      nreg0 = *(const short8*)(src + (size_t)(0 * 512 + tid) * 8);
      nreg1 = *(const short8*)(src + (size_t)(1 * 512 + tid) * 8);
    }

    short8 af[4], bf[4];
#pragma unroll
    for (int ms = 0; ms < 4; ++ms)
      af[ms] = *(const short8*)(
          wbuf[cur] + (size_t)(kg * 256 + oq * 64 + ms * 16 + ln) * 8);
#pragma unroll
    for (int ns = 0; ns < 4; ++ns)
      bf[ns] = *(const short8*)(
          xs + ((q * 4 + kg) * 130 + wh * 64 + ns * 16 + ln + k) * 8);
#pragma unroll
    for (int ms = 0; ms < 4; ++ms)
#pragma unroll
      for (int ns = 0; ns < 4; ++ns)
        acc[ms][ns] = __builtin_amdgcn_mfma_f32_16x16x32_bf16(
            af[ms], bf[ns], acc[ms][ns], 0, 0, 0);

    if (c < 11) {
      *(short8*)(wbuf[cur ^ 1] + (size_t)(0 * 512 + tid) * 8) = nreg0;
      *(short8*)(wbuf[cur ^ 1] + (size_t)(1 * 512 + tid) * 8) = nreg1;
    }
    __syncthreads();
  }

  // r2
  float zs = 0.f;
#pragma unroll
  for (int t = 0; t < 16; ++t) zs += racc2[b * 16 + t];
  float z = zs * (1.f / (float)WLEN) + fcb[0];
  float r2v = 1.f / (1.f + expf(-z));

#pragma unroll
  for (int ms = 0; ms < 4; ++ms) {
    const int o0 = oq * 64 + ms * 16 + kg * 4;
    float a_[4], c_[4];
#pragma unroll
    for (int rr = 0; rr < 4; ++rr) {
      int o = o0 + rr;
      float s = g[o] * rsqrtf(rv[o] + 1e-5f);
      a_[rr] = r2v * s;
      c_[rr] = (r2v * bias[o] - rm[o]) * s + be[o];
    }
#pragma unroll
    for (int np = 0; np < 2; ++np) {  // ns pairs (0,1), (2,3)
      float m0[4], m1[4];
#pragma unroll
      for (int half = 0; half < 2; ++half) {
        int ns = np * 2 + half;
#pragma unroll
        for (int rr = 0; rr < 4; ++rr) {
          float v = acc[ms][ns][rr] * a_[rr] + c_[rr];
          v = v >= 0.f ? v : 0.1f * v;
          float m = fmaxf(v, __shfl_xor(v, 1));
          if (half == 0) m0[rr] = m; else m1[rr] = m;
        }
      }
      const int pc = (w0 >> 1) + wh * 32 + np * 16 + ln;
#pragma unroll
      for (int rr = 0; rr < 4; ++rr) {
        int src = kg * 16 + ((ln & 7) << 1);
        float aa = __shfl(m0[rr], src);
        float bb = __shfl(m1[rr], src);
        float val = (ln < 8) ? aa : bb;
        out[((size_t)(b * 256 + o0 + rr)) * (WLEN / 2) + pc] = val;
      }
    }
  }
}

// ---------------------------------------------------------------------------
extern "C" void kernel_launch(void* const* d_in, const int* in_sizes, int n_in,
                              void* d_out, int out_size, void* d_ws, size_t ws_size,
                              hipStream_t stream) {
  const float* x    = (const float*)d_in[0];
  const float* w1   = (const float*)d_in[1];
  const float* b1   = (const float*)d_in[2];
  const float* fcw1 = (const float*)d_in[3];
  const float* fcb1 = (const float*)d_in[4];
  const float* g1   = (const float*)d_in[5];
  const float* be1  = (const float*)d_in[6];
  const float* rm1  = (const float*)d_in[7];
  const float* rv1  = (const float*)d_in[8];
  const float* w2   = (const float*)d_in[9];
  const float* b2   = (const float*)d_in[10];
  const float* fcw2 = (const float*)d_in[11];
  const float* fcb2 = (const float*)d_in[12];
  const float* g2   = (const float*)d_in[13];
  const float* be2  = (const float*)d_in[14];
  const float* rm2  = (const float*)d_in[15];
  const float* rv2  = (const float*)d_in[16];
  float* out = (float*)d_out;

  char* ws = (char*)d_ws;
  short* y1p   = (short*)ws;                          // 32*16*2048*8*2 = 16 MiB
  short* wp1   = (short*)(ws + (size_t)16 * 1024 * 1024);            // 48 KiB
  short* wp2   = (short*)(ws + (size_t)16 * 1024 * 1024 + 65536);    // 192 KiB
  float* racc1 = (float*)(ws + (size_t)16 * 1024 * 1024 + 327680);   // 256 f
  float* racc2 = racc1 + 256;                                        // 512 f

  fused_prep<<<316, 256, 0, stream>>>(w1, w2, x, fcw1, wp1, wp2, racc1);
  conv1_mfma<<<dim3(16, 32), 512, 0, stream>>>(
      x, wp1, b1, g1, be1, rm1, rv1, racc1, fcb1, fcw2, y1p, racc2);
  conv2_mfma<<<dim3(16, 32), 512, 0, stream>>>(
      y1p, wp2, b2, g2, be2, rm2, rv2, racc2, fcb2, out);
}